// Round 4
// baseline (326.101 us; speedup 1.0000x reference)
//
#include <hip/hip_runtime.h>

// LSTM (B=4096, T=512, IN=4, H=50) + final FC, MFMA v4.
// gates[200x16] = Wcat[200x64] @ [h;x][64x16] per step, mfma_f32_16x16x32_bf16.
// k-layout: k=0..49 h (identity), k=56..59 x, rest zero.
// v4 change: NO in-loop global loads — x staged once (coalesced) into a bf16
// LDS plane; lg==3 lanes compose their B-fragment from the plane directly.
// R2/R3 post-mortem: per-step 1195cyc was the uncoalesced per-step x load's
// vmcnt stall inside the barrier lockstep, not LDS conflicts / VALU issue.

#define HID  50
#define NROW 200
#define TT   512
#define NIN  4
#define BT   16
#define KD   72      // shorts per h-row (144B, stride 36 dwords -> 2-way max)
#define XSTR 17      // x-plane row stride in uint2 (padded: conflict-free reads)
#define NW   8

typedef float f32x4 __attribute__((ext_vector_type(4)));
typedef short s16x8 __attribute__((ext_vector_type(8)));

__device__ __forceinline__ unsigned short f2bf(float f) {
    unsigned u = __builtin_bit_cast(unsigned, f);
    return (unsigned short)((u + 0x7FFF + ((u >> 16) & 1)) >> 16);
}
__device__ __forceinline__ float fast_sigmoid(float v) {
    float e = __builtin_amdgcn_exp2f(v * -1.442695040888963f);
    return __builtin_amdgcn_rcpf(1.0f + e);
}
__device__ __forceinline__ float fast_tanh(float v) {
    float e = __builtin_amdgcn_exp2f(v * -2.885390081777927f);
    return 2.0f * __builtin_amdgcn_rcpf(1.0f + e) - 1.0f;
}

// weight for interleaved A-row rowp (=4u+g) at k-position kp
__device__ __forceinline__ float wval(const float* W_hh, const float* W_ih,
                                      int rowp, int kp) {
    if (rowp >= NROW) return 0.0f;
    const int u = rowp >> 2, g = rowp & 3;
    if (kp < HID)              return W_hh[(g * HID + u) * HID + kp];
    if (kp >= 56 && kp < 60)   return W_ih[(g * HID + u) * NIN + (kp - 56)];
    return 0.0f;
}

__global__ __launch_bounds__(64 * NW, 2)
void lstm_mfma4(const float* __restrict__ x,     // [B,T,4]
                const float* __restrict__ W_ih,  // [200,4]
                const float* __restrict__ W_hh,  // [200,50]
                const float* __restrict__ b_ih,  // [200]
                const float* __restrict__ b_hh,  // [200]
                const float* __restrict__ W_fc,  // [1,50]
                const float* __restrict__ b_fc,  // [1]
                float* __restrict__ out)         // [B,1]
{
    __shared__ __align__(16) unsigned short buf[2][BT][KD];  // h (bf16), dbuf
    __shared__ uint2 xpl[TT * XSTR];                         // x plane (bf16)
    __shared__ float red[BT];

    const int tid = threadIdx.x;
    const int w   = tid >> 6;
    const int l   = tid & 63;
    const int lr  = l & 15;          // batch col / A row-in-tile
    const int lg  = l >> 4;          // k-group 0..3 / D row-group
    const int b0  = blockIdx.x * BT;

    for (int i = tid; i < 2 * BT * KD; i += 64 * NW)
        ((unsigned short*)buf)[i] = 0;
    if (tid < BT) red[tid] = 0.0f;

    // ---- one-time coalesced x staging: 8192 float4 -> bf16 LDS plane ----
    {
        const float4* xs = (const float4*)(x + (size_t)b0 * TT * NIN);
#pragma unroll
        for (int it = 0; it < (TT * BT) / (64 * NW); ++it) {   // 16 iters
            const int e = tid + it * 64 * NW;
            const float4 v = xs[e];                            // x[b][t][0..3]
            unsigned lo, hi;
            asm("v_cvt_pk_bf16_f32 %0, %1, %2" : "=v"(lo) : "v"(v.x), "v"(v.y));
            asm("v_cvt_pk_bf16_f32 %0, %1, %2" : "=v"(hi) : "v"(v.z), "v"(v.w));
            const int brel = e >> 9, t = e & (TT - 1);
            xpl[t * XSTR + brel] = make_uint2(lo, hi);
        }
    }

    const bool two = (w < 5);
    const int  T0  = two ? w : (w + 5);   // waves 5,6,7 -> tiles 10,11,12
    const int  T1  = w + 5;               // valid only when two

    // ---- preload A fragments, bias, W_fc (once, to registers) ----
    s16x8 af0[2], af1[2];
    f32x4 bias0, bias1 = {0.f, 0.f, 0.f, 0.f};
    float wfc0 = 0.0f, wfc1 = 0.0f;
    {
        const int rowp = 16 * T0 + lr;
#pragma unroll
        for (int kh = 0; kh < 2; ++kh) {
            s16x8 f;
#pragma unroll
            for (int j = 0; j < 8; ++j)
                f[j] = (short)f2bf(wval(W_hh, W_ih, rowp, 32 * kh + 8 * lg + j));
            af0[kh] = f;
        }
#pragma unroll
        for (int r = 0; r < 4; ++r) {
            const int rr = 16 * T0 + 4 * lg + r;
            bias0[r] = (rr < NROW) ? (b_ih[(rr & 3) * HID + (rr >> 2)] +
                                      b_hh[(rr & 3) * HID + (rr >> 2)]) : 0.0f;
        }
        const int u = 4 * T0 + lg;
        wfc0 = (u < HID) ? W_fc[u] : 0.0f;
    }
    if (two) {
        const int rowp = 16 * T1 + lr;
#pragma unroll
        for (int kh = 0; kh < 2; ++kh) {
            s16x8 f;
#pragma unroll
            for (int j = 0; j < 8; ++j)
                f[j] = (short)f2bf(wval(W_hh, W_ih, rowp, 32 * kh + 8 * lg + j));
            af1[kh] = f;
        }
#pragma unroll
        for (int r = 0; r < 4; ++r) {
            const int rr = 16 * T1 + 4 * lg + r;
            bias1[r] = (rr < NROW) ? (b_ih[(rr & 3) * HID + (rr >> 2)] +
                                      b_hh[(rr & 3) * HID + (rr >> 2)]) : 0.0f;
        }
        const int u = 4 * T1 + lg;
        wfc1 = (u < HID) ? W_fc[u] : 0.0f;
    }
    __syncthreads();   // xpl + zeroed buf visible to all

    float c0 = 0.f, h0 = 0.f, c1 = 0.f, h1 = 0.f;

    for (int t = 0; t < TT; ++t) {
        const int p = t & 1;

        const s16x8 bf0v = *(const s16x8*)&buf[p][lr][8 * lg];   // k 0..31
        s16x8 bf1v;                                              // k 32..63
        if (lg == 3) {  // k 56..59 = x_t (from plane), 60..63 = 0
            const uint2 xv = xpl[t * XSTR + lr];
            const uint4 tmp = {xv.x, xv.y, 0u, 0u};
            bf1v = __builtin_bit_cast(s16x8, tmp);
        } else {        // k 32..55: h32..49 + zero pad (slots 50..55 stay 0)
            bf1v = *(const s16x8*)&buf[p][lr][32 + 8 * lg];
        }

        f32x4 a0 = bias0;
        a0 = __builtin_amdgcn_mfma_f32_16x16x32_bf16(af0[0], bf0v, a0, 0, 0, 0);
        a0 = __builtin_amdgcn_mfma_f32_16x16x32_bf16(af0[1], bf1v, a0, 0, 0, 0);
        f32x4 a1;
        if (two) {
            a1 = bias1;
            a1 = __builtin_amdgcn_mfma_f32_16x16x32_bf16(af1[0], bf0v, a1, 0, 0, 0);
            a1 = __builtin_amdgcn_mfma_f32_16x16x32_bf16(af1[1], bf1v, a1, 0, 0, 0);
        }

        {
            const float gi = fast_sigmoid(a0[0]);
            const float gf = fast_sigmoid(a0[1]);
            const float gg = fast_tanh(a0[2]);
            const float go = fast_sigmoid(a0[3]);
            c0 = gf * c0 + gi * gg;
            h0 = go * fast_tanh(c0);
            buf[p ^ 1][lr][4 * T0 + lg] = f2bf(h0);   // pad units write h=0
        }
        if (two) {
            const float gi = fast_sigmoid(a1[0]);
            const float gf = fast_sigmoid(a1[1]);
            const float gg = fast_tanh(a1[2]);
            const float go = fast_sigmoid(a1[3]);
            c1 = gf * c1 + gi * gg;
            h1 = go * fast_tanh(c1);
            buf[p ^ 1][lr][4 * T1 + lg] = f2bf(h1);
        }
        __syncthreads();
    }

    // ---- FC epilogue: out[b] = sum_u W_fc[u]*h_T[u][b] + b_fc ----
    float partial = wfc0 * h0 + wfc1 * h1;   // pad units contribute 0
    partial += __shfl_down(partial, 32);
    partial += __shfl_down(partial, 16);
    if (l < 16) atomicAdd(&red[l], partial);
    __syncthreads();
    if (tid < BT) out[b0 + tid] = red[tid] + b_fc[0];
}

extern "C" void kernel_launch(void* const* d_in, const int* in_sizes, int n_in,
                              void* d_out, int out_size, void* d_ws, size_t ws_size,
                              hipStream_t stream) {
    const float* x    = (const float*)d_in[0];
    const float* W_ih = (const float*)d_in[1];
    const float* W_hh = (const float*)d_in[2];
    const float* b_ih = (const float*)d_in[3];
    const float* b_hh = (const float*)d_in[4];
    const float* W_fc = (const float*)d_in[5];
    const float* b_fc = (const float*)d_in[6];
    float* out        = (float*)d_out;

    const int B = in_sizes[0] / (TT * NIN);   // 4096
    lstm_mfma4<<<B / BT, 64 * NW, 0, stream>>>(x, W_ih, W_hh, b_ih, b_hh, W_fc, b_fc, out);
}